// Round 1
// baseline (329.689 us; speedup 1.0000x reference)
//
#include <hip/hip_runtime.h>
#include <hip/hip_bf16.h>

#define NN 50000
#define NE 600000

typedef __attribute__((ext_vector_type(4))) float f32x4;
typedef __attribute__((ext_vector_type(8))) __bf16 bf16x8;

__device__ __forceinline__ bf16x8 load_afrag(const float* base) {
  f32x4 x0 = *(const f32x4*)(base);
  f32x4 x1 = *(const f32x4*)(base + 4);
  bf16x8 a;
  a[0] = (__bf16)x0.x; a[1] = (__bf16)x0.y; a[2] = (__bf16)x0.z; a[3] = (__bf16)x0.w;
  a[4] = (__bf16)x1.x; a[5] = (__bf16)x1.y; a[6] = (__bf16)x1.z; a[7] = (__bf16)x1.w;
  return a;
}

// ---------- dense [N,128] @ [128,128], bf16 MFMA, fp32 in/out ----------
// BR bit0 = add bias, bit1 = relu
template<int BR>
__global__ __launch_bounds__(256) void k_mm128(const float* X, const float* __restrict__ W,
                                               const float* __restrict__ bias, float* Y, int nrows) {
  __shared__ __bf16 wt[128][136];  // wt[j][k] = W[k][j], +8 pad kills bank conflicts
  int tid = threadIdx.x;
  const f32x4* W4 = (const f32x4*)W;
  for (int i = tid; i < 4096; i += 256) {
    int k = i >> 5, j = (i & 31) << 2;
    f32x4 w = W4[i];
    wt[j + 0][k] = (__bf16)w.x;
    wt[j + 1][k] = (__bf16)w.y;
    wt[j + 2][k] = (__bf16)w.z;
    wt[j + 3][k] = (__bf16)w.w;
  }
  __syncthreads();
  int lane = tid & 63;
  int strip = blockIdx.x * 4 + (tid >> 6);
  if (strip * 16 >= nrows) return;
  int r16 = lane & 15, g = lane >> 4;
  const float* xbase = X + (size_t)(strip * 16 + r16) * 128 + g * 8;
  bf16x8 a[4];
#pragma unroll
  for (int ks = 0; ks < 4; ks++) a[ks] = load_afrag(xbase + ks * 32);
  f32x4 acc[8];
#pragma unroll
  for (int ct = 0; ct < 8; ct++) acc[ct] = (f32x4){0.f, 0.f, 0.f, 0.f};
#pragma unroll
  for (int ct = 0; ct < 8; ct++) {
    const __bf16* wrow = &wt[ct * 16 + r16][g * 8];
#pragma unroll
    for (int ks = 0; ks < 4; ks++) {
      bf16x8 b = *(const bf16x8*)(wrow + ks * 32);
      acc[ct] = __builtin_amdgcn_mfma_f32_16x16x32_bf16(a[ks], b, acc[ct], 0, 0, 0);
    }
  }
  int rbase = strip * 16 + g * 4;
#pragma unroll
  for (int ct = 0; ct < 8; ct++) {
    int col = ct * 16 + r16;
    float bv = (BR & 1) ? bias[col] : 0.f;
#pragma unroll
    for (int i = 0; i < 4; i++) {
      float v = acc[ct][i] + bv;
      if (BR & 2) v = fmaxf(v, 0.f);
      Y[(size_t)(rbase + i) * 128 + col] = v;
    }
  }
}

// ---------- task heads: [N,128] @ [128,50] -> y[t][n][c] ----------
__global__ __launch_bounds__(256) void k_head(const float* __restrict__ H, const float* __restrict__ TW,
                                              const float* __restrict__ TB, float* __restrict__ Y) {
  __shared__ __bf16 wt[64][136];  // wt[o][k] = task_w[o/10][k][o%10], o<50; else 0
  int tid = threadIdx.x;
  for (int i = tid; i < 8192; i += 256) {
    int o = i >> 7, k = i & 127;
    float v = 0.f;
    if (o < 50) v = TW[(o / 10) * 1280 + k * 10 + (o % 10)];
    wt[o][k] = (__bf16)v;
  }
  __syncthreads();
  int lane = tid & 63;
  int strip = blockIdx.x * 4 + (tid >> 6);
  if (strip * 16 >= NN) return;
  int r16 = lane & 15, g = lane >> 4;
  const float* xbase = H + (size_t)(strip * 16 + r16) * 128 + g * 8;
  bf16x8 a[4];
#pragma unroll
  for (int ks = 0; ks < 4; ks++) a[ks] = load_afrag(xbase + ks * 32);
  f32x4 acc[4];
#pragma unroll
  for (int ct = 0; ct < 4; ct++) acc[ct] = (f32x4){0.f, 0.f, 0.f, 0.f};
#pragma unroll
  for (int ct = 0; ct < 4; ct++) {
    const __bf16* wrow = &wt[ct * 16 + r16][g * 8];
#pragma unroll
    for (int ks = 0; ks < 4; ks++) {
      bf16x8 b = *(const bf16x8*)(wrow + ks * 32);
      acc[ct] = __builtin_amdgcn_mfma_f32_16x16x32_bf16(a[ks], b, acc[ct], 0, 0, 0);
    }
  }
  int rbase = strip * 16 + g * 4;
#pragma unroll
  for (int ct = 0; ct < 4; ct++) {
    int o = ct * 16 + r16;
    if (o < 50) {
      int t = o / 10, c = o % 10;
      float tb = TB[o];
#pragma unroll
      for (int i = 0; i < 4; i++) {
        Y[(size_t)t * (NN * 10) + (size_t)(rbase + i) * 10 + c] = acc[ct][i] + tb;
      }
    }
  }
}

// ---------- CSR pull aggregation: one wave per node, lanes = 2 feature dims ----------
__global__ __launch_bounds__(256) void k_agg(const float* __restrict__ T, const int* __restrict__ rp,
                                             const int* __restrict__ colv, const float* __restrict__ nrmv,
                                             const float* __restrict__ dinv, const float* __restrict__ bias,
                                             float* __restrict__ H) {
  int node = blockIdx.x * 4 + (threadIdx.x >> 6);
  int lane = threadIdx.x & 63;
  const float2* T2 = (const float2*)T;
  float di = dinv[node];
  float sl = di * di;  // self-loop norm
  float2 t0 = T2[(size_t)node * 64 + lane];
  float2 acc = make_float2(t0.x * sl, t0.y * sl);
  int s = rp[node], e = rp[node + 1];
  for (int i = s; i < e; i++) {
    int c = colv[i];
    float w = nrmv[i];
    float2 v = T2[(size_t)c * 64 + lane];
    acc.x = fmaf(v.x, w, acc.x);
    acc.y = fmaf(v.y, w, acc.y);
  }
  const float2* B2 = (const float2*)bias;
  float2 b = B2[lane];
  float2 o = make_float2(fmaxf(acc.x + b.x, 0.f), fmaxf(acc.y + b.y, 0.f));
  ((float2*)H)[(size_t)node * 64 + lane] = o;
}

// ---------- CSR build ----------
__global__ void k_count(const int* __restrict__ dstv, int* __restrict__ degi) {
  int e = blockIdx.x * 256 + threadIdx.x;
  if (e < NE) atomicAdd(&degi[dstv[e]], 1);
}

__global__ __launch_bounds__(256) void k_scan1(const int* __restrict__ degi, int* __restrict__ rp,
                                               int* __restrict__ bsum) {
  __shared__ int s[256];
  int gid = blockIdx.x * 256 + threadIdx.x;
  int v = (gid < NN) ? degi[gid] : 0;
  s[threadIdx.x] = v;
  __syncthreads();
  int acc = v;
  for (int off = 1; off < 256; off <<= 1) {
    int add = (threadIdx.x >= off) ? s[threadIdx.x - off] : 0;
    __syncthreads();
    acc += add;
    s[threadIdx.x] = acc;
    __syncthreads();
  }
  if (gid < NN) rp[gid + 1] = acc;
  if (threadIdx.x == 255) bsum[blockIdx.x] = acc;
}

__global__ __launch_bounds__(256) void k_scan2(int* __restrict__ bsum, int nb) {
  __shared__ int s[256];
  int v = (threadIdx.x < nb) ? bsum[threadIdx.x] : 0;
  s[threadIdx.x] = v;
  __syncthreads();
  int acc = v;
  for (int off = 1; off < 256; off <<= 1) {
    int add = (threadIdx.x >= off) ? s[threadIdx.x - off] : 0;
    __syncthreads();
    acc += add;
    s[threadIdx.x] = acc;
    __syncthreads();
  }
  if (threadIdx.x < nb) bsum[threadIdx.x] = acc - v;  // exclusive
}

__global__ void k_scan3(int* __restrict__ rp, const int* __restrict__ bsum) {
  int gid = blockIdx.x * 256 + threadIdx.x;
  if (gid < NN) rp[gid + 1] += bsum[blockIdx.x];
  if (gid == 0) rp[0] = 0;
}

__global__ void k_prep(const int* __restrict__ rp, const int* __restrict__ degi,
                       int* __restrict__ cur, float* __restrict__ dinv) {
  int i = blockIdx.x * 256 + threadIdx.x;
  if (i < NN) {
    cur[i] = rp[i];
    dinv[i] = rsqrtf((float)(degi[i] + 1));  // +1 self-loop; always > 0
  }
}

__global__ void k_fill(const int* __restrict__ srcv, const int* __restrict__ dstv,
                       int* __restrict__ cur, int* __restrict__ colv, float* __restrict__ nrmv,
                       const float* __restrict__ dinv) {
  int e = blockIdx.x * 256 + threadIdx.x;
  if (e < NE) {
    int s = srcv[e], d = dstv[e];
    int p = atomicAdd(&cur[d], 1);
    colv[p] = s;
    nrmv[p] = dinv[s] * dinv[d];
  }
}

extern "C" void kernel_launch(void* const* d_in, const int* in_sizes, int n_in,
                              void* d_out, int out_size, void* d_ws, size_t ws_size,
                              hipStream_t stream) {
  (void)in_sizes; (void)n_in; (void)out_size; (void)ws_size;
  const float* x   = (const float*)d_in[0];
  const int*   ei  = (const int*)d_in[1];
  const float* w1  = (const float*)d_in[2];
  const float* b1  = (const float*)d_in[3];
  const float* w2  = (const float*)d_in[4];
  const float* b2  = (const float*)d_in[5];
  const float* fw1 = (const float*)d_in[6];
  const float* fb1 = (const float*)d_in[7];
  const float* fw2 = (const float*)d_in[8];
  const float* fb2 = (const float*)d_in[9];
  const float* tw  = (const float*)d_in[10];
  const float* tb  = (const float*)d_in[11];
  const int* srcv = ei;
  const int* dstv = ei + NE;

  char* wsb = (char*)d_ws;
  float* bufT = (float*)(wsb + 0);          // 25,600,000 B
  int*   degi = (int*)(wsb + 25600000);     //   200,000 B
  int*   rp   = (int*)(wsb + 25800192);     //   200,004 B
  int*   cur  = (int*)(wsb + 26000640);     //   200,000 B
  int*   bsum = (int*)(wsb + 26200832);     //       784 B
  float* dinv = (float*)(wsb + 26201856);   //   200,000 B
  int*   colv = (int*)(wsb + 26402048);     // 2,400,000 B
  float* nrmv = (float*)(wsb + 28802048);   // 2,400,000 B
  // total ~31.2 MB

  float* y_out = (float*)d_out;              // [5,50000,10]
  float* feat  = (float*)d_out + 2500000;    // [50000,128] feature_x (also used as h buffer)

  // --- degree + CSR build (rebuilt every call; deterministic work) ---
  hipMemsetAsync(degi, 0, NN * sizeof(int), stream);
  k_count<<<(NE + 255) / 256, 256, 0, stream>>>(dstv, degi);
  k_scan1<<<196, 256, 0, stream>>>(degi, rp, bsum);
  k_scan2<<<1, 256, 0, stream>>>(bsum, 196);
  k_scan3<<<196, 256, 0, stream>>>(rp, bsum);
  k_prep<<<196, 256, 0, stream>>>(rp, degi, cur, dinv);
  k_fill<<<(NE + 255) / 256, 256, 0, stream>>>(srcv, dstv, cur, colv, nrmv, dinv);

  // --- GCN layer 1: t1 = x@w1 ; h1 = relu(agg + b1) ---
  k_mm128<0><<<782, 256, 0, stream>>>(x, w1, nullptr, bufT, NN);
  k_agg<<<12500, 256, 0, stream>>>(bufT, rp, colv, nrmv, dinv, b1, feat);
  // --- GCN layer 2 ---
  k_mm128<0><<<782, 256, 0, stream>>>(feat, w2, nullptr, bufT, NN);
  k_agg<<<12500, 256, 0, stream>>>(bufT, rp, colv, nrmv, dinv, b2, feat);
  // --- fc1 (feature_x, in-place ok: each wave reads exactly its own 16 rows first) ---
  k_mm128<3><<<782, 256, 0, stream>>>(feat, fw1, fb1, feat, NN);
  // --- fc2 ---
  k_mm128<3><<<782, 256, 0, stream>>>(feat, fw2, fb2, bufT, NN);
  // --- heads ---
  k_head<<<782, 256, 0, stream>>>(bufT, tw, tb, y_out);
}

// Round 2
// 243.024 us; speedup vs baseline: 1.3566x; 1.3566x over previous
//
#include <hip/hip_runtime.h>
#include <hip/hip_bf16.h>

#define NN 50000
#define NE 600000

typedef __attribute__((ext_vector_type(4))) float f32x4;
typedef __attribute__((ext_vector_type(8))) __bf16 bf16x8;

__device__ __forceinline__ bf16x8 load_afrag_f32(const float* base) {
  f32x4 x0 = *(const f32x4*)(base);
  f32x4 x1 = *(const f32x4*)(base + 4);
  bf16x8 a;
  a[0] = (__bf16)x0.x; a[1] = (__bf16)x0.y; a[2] = (__bf16)x0.z; a[3] = (__bf16)x0.w;
  a[4] = (__bf16)x1.x; a[5] = (__bf16)x1.y; a[6] = (__bf16)x1.z; a[7] = (__bf16)x1.w;
  return a;
}

__device__ __forceinline__ unsigned pack2bf16(float x, float y) {
  __bf16 lo = (__bf16)x, hi = (__bf16)y;
  unsigned short ul = __builtin_bit_cast(unsigned short, lo);
  unsigned short uh = __builtin_bit_cast(unsigned short, hi);
  return (unsigned)ul | ((unsigned)uh << 16);
}

// ---------- dense [N,128] @ [128,128], bf16 MFMA, bf16 (and optional fp32) out ----------
// BR bit0 = add bias, bit1 = relu. IN_BF16: input dtype. DUAL: also write fp32 copy.
template<int BR, bool IN_BF16, bool DUAL>
__global__ __launch_bounds__(256) void k_mm128(const void* __restrict__ Xv, const float* __restrict__ W,
                                               const float* __restrict__ bias, __bf16* __restrict__ Y,
                                               float* __restrict__ Yf, int nrows) {
  __shared__ __bf16 wt[128][136];  // wt[j][k] = W[k][j], +8 pad kills bank conflicts
  int tid = threadIdx.x;
  const f32x4* W4 = (const f32x4*)W;
  for (int i = tid; i < 4096; i += 256) {
    int k = i >> 5, j = (i & 31) << 2;
    f32x4 w = W4[i];
    wt[j + 0][k] = (__bf16)w.x;
    wt[j + 1][k] = (__bf16)w.y;
    wt[j + 2][k] = (__bf16)w.z;
    wt[j + 3][k] = (__bf16)w.w;
  }
  __syncthreads();
  int lane = tid & 63;
  int strip = blockIdx.x * 4 + (tid >> 6);
  if (strip * 16 >= nrows) return;
  int r16 = lane & 15, g = lane >> 4;
  bf16x8 a[4];
  if constexpr (IN_BF16) {
    const __bf16* xb = (const __bf16*)Xv + (size_t)(strip * 16 + r16) * 128 + g * 8;
#pragma unroll
    for (int ks = 0; ks < 4; ks++) a[ks] = *(const bf16x8*)(xb + ks * 32);
  } else {
    const float* xb = (const float*)Xv + (size_t)(strip * 16 + r16) * 128 + g * 8;
#pragma unroll
    for (int ks = 0; ks < 4; ks++) a[ks] = load_afrag_f32(xb + ks * 32);
  }
  f32x4 acc[8];
#pragma unroll
  for (int ct = 0; ct < 8; ct++) acc[ct] = (f32x4){0.f, 0.f, 0.f, 0.f};
#pragma unroll
  for (int ct = 0; ct < 8; ct++) {
    const __bf16* wrow = &wt[ct * 16 + r16][g * 8];
#pragma unroll
    for (int ks = 0; ks < 4; ks++) {
      bf16x8 b = *(const bf16x8*)(wrow + ks * 32);
      acc[ct] = __builtin_amdgcn_mfma_f32_16x16x32_bf16(a[ks], b, acc[ct], 0, 0, 0);
    }
  }
  int rbase = strip * 16 + g * 4;
#pragma unroll
  for (int ct = 0; ct < 8; ct++) {
    int col = ct * 16 + r16;
    float bv = (BR & 1) ? bias[col] : 0.f;
#pragma unroll
    for (int i = 0; i < 4; i++) {
      float v = acc[ct][i] + bv;
      if (BR & 2) v = fmaxf(v, 0.f);
      size_t idx = (size_t)(rbase + i) * 128 + col;
      Y[idx] = (__bf16)v;
      if constexpr (DUAL) Yf[idx] = v;
    }
  }
}

// ---------- task heads: bf16 [N,128] @ [128,50] -> y[t][n][c] fp32 ----------
__global__ __launch_bounds__(256) void k_head(const __bf16* __restrict__ H, const float* __restrict__ TW,
                                              const float* __restrict__ TB, float* __restrict__ Y) {
  __shared__ __bf16 wt[64][136];  // wt[o][k] = task_w[o/10][k][o%10], o<50; else 0
  int tid = threadIdx.x;
  for (int i = tid; i < 8192; i += 256) {
    int o = i >> 7, k = i & 127;
    float v = 0.f;
    if (o < 50) v = TW[(o / 10) * 1280 + k * 10 + (o % 10)];
    wt[o][k] = (__bf16)v;
  }
  __syncthreads();
  int lane = tid & 63;
  int strip = blockIdx.x * 4 + (tid >> 6);
  if (strip * 16 >= NN) return;
  int r16 = lane & 15, g = lane >> 4;
  const __bf16* xb = H + (size_t)(strip * 16 + r16) * 128 + g * 8;
  bf16x8 a[4];
#pragma unroll
  for (int ks = 0; ks < 4; ks++) a[ks] = *(const bf16x8*)(xb + ks * 32);
  f32x4 acc[4];
#pragma unroll
  for (int ct = 0; ct < 4; ct++) acc[ct] = (f32x4){0.f, 0.f, 0.f, 0.f};
#pragma unroll
  for (int ct = 0; ct < 4; ct++) {
    const __bf16* wrow = &wt[ct * 16 + r16][g * 8];
#pragma unroll
    for (int ks = 0; ks < 4; ks++) {
      bf16x8 b = *(const bf16x8*)(wrow + ks * 32);
      acc[ct] = __builtin_amdgcn_mfma_f32_16x16x32_bf16(a[ks], b, acc[ct], 0, 0, 0);
    }
  }
  int rbase = strip * 16 + g * 4;
#pragma unroll
  for (int ct = 0; ct < 4; ct++) {
    int o = ct * 16 + r16;
    if (o < 50) {
      int t = o / 10, c = o % 10;
      float tb = TB[o];
#pragma unroll
      for (int i = 0; i < 4; i++) {
        Y[(size_t)t * (NN * 10) + (size_t)(rbase + i) * 10 + c] = acc[ct][i] + tb;
      }
    }
  }
}

// ---------- CSR pull aggregation, bf16 rows: one wave per node ----------
__global__ __launch_bounds__(256) void k_agg(const unsigned* __restrict__ T, const int* __restrict__ rp,
                                             const int2* __restrict__ edg, const float* __restrict__ dinv,
                                             const float* __restrict__ bias, unsigned* __restrict__ H) {
  int node = blockIdx.x * 4 + (threadIdx.x >> 6);
  int lane = threadIdx.x & 63;
  float di = dinv[node];
  float sl = di * di;  // self-loop norm
  unsigned t0 = T[node * 64 + lane];
  float ax = __uint_as_float(t0 << 16) * sl;
  float ay = __uint_as_float(t0 & 0xffff0000u) * sl;
  int s = rp[node], e = rp[node + 1];
  int i = s;
  for (; i + 4 <= e; i += 4) {  // 4 outstanding row loads
    int2 e0 = edg[i], e1 = edg[i + 1], e2 = edg[i + 2], e3 = edg[i + 3];
    unsigned v0 = T[e0.x * 64 + lane];
    unsigned v1 = T[e1.x * 64 + lane];
    unsigned v2 = T[e2.x * 64 + lane];
    unsigned v3 = T[e3.x * 64 + lane];
    float w0 = __int_as_float(e0.y), w1 = __int_as_float(e1.y);
    float w2 = __int_as_float(e2.y), w3 = __int_as_float(e3.y);
    ax = fmaf(__uint_as_float(v0 << 16), w0, ax);
    ay = fmaf(__uint_as_float(v0 & 0xffff0000u), w0, ay);
    ax = fmaf(__uint_as_float(v1 << 16), w1, ax);
    ay = fmaf(__uint_as_float(v1 & 0xffff0000u), w1, ay);
    ax = fmaf(__uint_as_float(v2 << 16), w2, ax);
    ay = fmaf(__uint_as_float(v2 & 0xffff0000u), w2, ay);
    ax = fmaf(__uint_as_float(v3 << 16), w3, ax);
    ay = fmaf(__uint_as_float(v3 & 0xffff0000u), w3, ay);
  }
  for (; i < e; i++) {
    int2 ed = edg[i];
    float w = __int_as_float(ed.y);
    unsigned v = T[ed.x * 64 + lane];
    ax = fmaf(__uint_as_float(v << 16), w, ax);
    ay = fmaf(__uint_as_float(v & 0xffff0000u), w, ay);
  }
  float2 b = ((const float2*)bias)[lane];
  ax = fmaxf(ax + b.x, 0.f);
  ay = fmaxf(ay + b.y, 0.f);
  H[node * 64 + lane] = pack2bf16(ax, ay);
}

// ---------- CSR build ----------
__global__ void k_count(const int* __restrict__ dstv, int* __restrict__ degi) {
  int e = blockIdx.x * 256 + threadIdx.x;
  if (e < NE) atomicAdd(&degi[dstv[e]], 1);
}

__global__ __launch_bounds__(256) void k_scan1(const int* __restrict__ degi, int* __restrict__ rp,
                                               int* __restrict__ bsum) {
  __shared__ int s[256];
  int gid = blockIdx.x * 256 + threadIdx.x;
  int v = (gid < NN) ? degi[gid] : 0;
  s[threadIdx.x] = v;
  __syncthreads();
  int acc = v;
  for (int off = 1; off < 256; off <<= 1) {
    int add = (threadIdx.x >= off) ? s[threadIdx.x - off] : 0;
    __syncthreads();
    acc += add;
    s[threadIdx.x] = acc;
    __syncthreads();
  }
  if (gid < NN) rp[gid + 1] = acc;
  if (threadIdx.x == 255) bsum[blockIdx.x] = acc;
}

__global__ __launch_bounds__(256) void k_scan2(int* __restrict__ bsum, int nb) {
  __shared__ int s[256];
  int v = (threadIdx.x < nb) ? bsum[threadIdx.x] : 0;
  s[threadIdx.x] = v;
  __syncthreads();
  int acc = v;
  for (int off = 1; off < 256; off <<= 1) {
    int add = (threadIdx.x >= off) ? s[threadIdx.x - off] : 0;
    __syncthreads();
    acc += add;
    s[threadIdx.x] = acc;
    __syncthreads();
  }
  if (threadIdx.x < nb) bsum[threadIdx.x] = acc - v;  // exclusive
}

// scan finalize + cursor + dinv (fused)
__global__ void k_scan3p(int* __restrict__ rp, const int* __restrict__ bsum, const int* __restrict__ degi,
                         int* __restrict__ cur, float* __restrict__ dinv) {
  int gid = blockIdx.x * 256 + threadIdx.x;
  if (gid < NN) {
    int d = degi[gid];
    int v = rp[gid + 1] + bsum[blockIdx.x];  // inclusive prefix through gid
    rp[gid + 1] = v;
    cur[gid] = v - d;                        // exclusive prefix = row start
    dinv[gid] = rsqrtf((float)(d + 1));      // +1 self-loop; always > 0
  }
  if (gid == 0) rp[0] = 0;
}

__global__ void k_fill(const int* __restrict__ srcv, const int* __restrict__ dstv,
                       int* __restrict__ cur, int2* __restrict__ edg, const float* __restrict__ dinv) {
  int e = blockIdx.x * 256 + threadIdx.x;
  if (e < NE) {
    int s = srcv[e], d = dstv[e];
    int p = atomicAdd(&cur[d], 1);
    edg[p] = make_int2(s, __float_as_int(dinv[s] * dinv[d]));
  }
}

extern "C" void kernel_launch(void* const* d_in, const int* in_sizes, int n_in,
                              void* d_out, int out_size, void* d_ws, size_t ws_size,
                              hipStream_t stream) {
  (void)in_sizes; (void)n_in; (void)out_size; (void)ws_size;
  const float* x   = (const float*)d_in[0];
  const int*   ei  = (const int*)d_in[1];
  const float* w1  = (const float*)d_in[2];
  const float* b1  = (const float*)d_in[3];
  const float* w2  = (const float*)d_in[4];
  const float* b2  = (const float*)d_in[5];
  const float* fw1 = (const float*)d_in[6];
  const float* fb1 = (const float*)d_in[7];
  const float* fw2 = (const float*)d_in[8];
  const float* fb2 = (const float*)d_in[9];
  const float* tw  = (const float*)d_in[10];
  const float* tb  = (const float*)d_in[11];
  const int* srcv = ei;
  const int* dstv = ei + NE;

  char* wsb = (char*)d_ws;
  __bf16* bufT = (__bf16*)(wsb + 0);         // 12,800,000 B  [N,128] bf16
  __bf16* hbf  = (__bf16*)(wsb + 12800000);  // 12,800,000 B  [N,128] bf16
  int*    degi = (int*)(wsb + 25600000);     //    200,000 B
  int*    rp   = (int*)(wsb + 25800192);     //    200,004 B
  int*    cur  = (int*)(wsb + 26000640);     //    200,000 B
  int*    bsum = (int*)(wsb + 26200832);     //        784 B
  float*  dinv = (float*)(wsb + 26201856);   //    200,000 B
  int2*   edg  = (int2*)(wsb + 26402048);    //  4,800,000 B
  // total ~31.2 MB

  float* y_out = (float*)d_out;              // [5,50000,10]
  float* feat  = (float*)d_out + 2500000;    // [50000,128] feature_x fp32

  // --- CSR build (rebuilt every call; deterministic) ---
  hipMemsetAsync(degi, 0, NN * sizeof(int), stream);
  k_count<<<(NE + 255) / 256, 256, 0, stream>>>(dstv, degi);
  k_scan1<<<196, 256, 0, stream>>>(degi, rp, bsum);
  k_scan2<<<1, 256, 0, stream>>>(bsum, 196);
  k_scan3p<<<196, 256, 0, stream>>>(rp, bsum, degi, cur, dinv);
  k_fill<<<(NE + 255) / 256, 256, 0, stream>>>(srcv, dstv, cur, edg, dinv);

  // --- GCN layer 1 ---
  k_mm128<0, false, false><<<782, 256, 0, stream>>>(x, w1, nullptr, bufT, nullptr, NN);
  k_agg<<<12500, 256, 0, stream>>>((const unsigned*)bufT, rp, edg, dinv, b1, (unsigned*)hbf);
  // --- GCN layer 2 ---
  k_mm128<0, true, false><<<782, 256, 0, stream>>>(hbf, w2, nullptr, bufT, nullptr, NN);
  k_agg<<<12500, 256, 0, stream>>>((const unsigned*)bufT, rp, edg, dinv, b2, (unsigned*)hbf);
  // --- fc1: feature_x (fp32 out to d_out, bf16 in-place for fc2) ---
  k_mm128<3, true, true><<<782, 256, 0, stream>>>(hbf, fw1, fb1, hbf, feat, NN);
  // --- fc2 ---
  k_mm128<3, true, false><<<782, 256, 0, stream>>>(hbf, fw2, fb2, bufT, nullptr, NN);
  // --- heads ---
  k_head<<<782, 256, 0, stream>>>(bufT, tw, tb, y_out);
}